// Round 7
// baseline (587.230 us; speedup 1.0000x reference)
//
#include <hip/hip_runtime.h>
#include <hip/hip_bf16.h>

#define D_IN 384
#define D_H  64
#define BSH  7          // bucket shift: 128 nodes per bucket
#define BN   128        // nodes per bucket
#define NBLK 512        // chunks for the two-level counting sort
#define EBUF 4608       // staged edges per bucket (mean 4096, +8 sigma margin)

typedef __attribute__((ext_vector_type(8))) short short8;
typedef __attribute__((ext_vector_type(4))) float f32x4;

__device__ __forceinline__ unsigned f2bf(float f){
  unsigned u = __float_as_uint(f);
  u += 0x7fffu + ((u >> 16) & 1u);   // round-to-nearest-even
  return u >> 16;
}

// ---- K0: seed out with classifier bias ----
__global__ void k_oinit(float* out, const float* __restrict__ bc, int G){
  int g = blockIdx.x * blockDim.x + threadIdx.x;
  if (g < G) out[g] = bc[0];
}

// ---- K1: per-chunk LDS histogram of dst buckets -> hists[blk][NB] ----
__global__ __launch_bounds__(256) void k_bcount2(const int* __restrict__ ei,
                                                 int* __restrict__ hists,
                                                 int E, int NB, int chunk){
  __shared__ int hist[1024];
  const int blk = blockIdx.x;
  const int t = threadIdx.x;
  for (int i = t; i < NB; i += 256) hist[i] = 0;
  __syncthreads();
  const int cs = blk * chunk;
  const int ce = min(E, cs + chunk);
  for (int e = cs + t; e < ce; e += 256)
    atomicAdd(&hist[ei[E + e] >> BSH], 1);
  __syncthreads();
  for (int i = t; i < NB; i += 256)
    hists[(size_t)blk * NB + i] = hist[i];
}

// ---- K2: per-bucket scan across blocks -> offs[b][blk] (exclusive), bsum[b] ----
__global__ __launch_bounds__(NBLK) void k_blkscan(const int* __restrict__ hists,
                                                  int* __restrict__ offs,
                                                  int* __restrict__ bsum, int NB){
  __shared__ int sd[NBLK];
  const int b = blockIdx.x;
  const int t = threadIdx.x;
  int c = hists[(size_t)t * NB + b];
  sd[t] = c;
  __syncthreads();
  for (int off = 1; off < NBLK; off <<= 1){
    int v = (t >= off) ? sd[t - off] : 0;
    __syncthreads();
    sd[t] += v;
    __syncthreads();
  }
  offs[(size_t)b * NBLK + t] = sd[t] - c;   // exclusive within bucket
  if (t == NBLK - 1) bsum[b] = sd[t];
}

// ---- K3: single-block scan over bucket totals -> bstart ----
__global__ __launch_bounds__(1024) void k_bscan(const int* __restrict__ bsum,
                                                int* bstart, int NB, int E){
  __shared__ int sd[1024];
  int t = threadIdx.x;
  int c = (t < NB) ? bsum[t] : 0;
  sd[t] = c;
  __syncthreads();
  for (int off = 1; off < 1024; off <<= 1){
    int v = (t >= off) ? sd[t - off] : 0;
    __syncthreads();
    sd[t] += v;
    __syncthreads();
  }
  if (t < NB) bstart[t] = sd[t] - c;
  if (t == 0) bstart[NB] = E;
}

// ---- K4: rank-and-scatter; each (block,bucket) segment is single-CU-owned ----
__global__ __launch_bounds__(256) void k_bscatter2(const int* __restrict__ ei,
                                                   const int* __restrict__ bstart,
                                                   const int* __restrict__ offs,
                                                   unsigned* __restrict__ bscat,
                                                   int E, int NB, int chunk){
  __shared__ int lcur[1024];
  const int blk = blockIdx.x;
  const int t = threadIdx.x;
  for (int i = t; i < NB; i += 256)
    lcur[i] = bstart[i] + offs[(size_t)i * NBLK + blk];
  __syncthreads();
  const int cs = blk * chunk;
  const int ce = min(E, cs + chunk);
  for (int e = cs + t; e < ce; e += 256){
    int s = ei[e];
    int d = ei[E + e];
    int b = d >> BSH;
    int pos = atomicAdd(&lcur[b], 1);
    bscat[pos] = ((unsigned)(d & (BN - 1)) << 17) | (unsigned)s;
  }
}

// ---- K5: per-bucket counting sort -> node-major csr (BYTE offsets src<<7),
//          rowstart, dis ----
__global__ __launch_bounds__(256) void k_nodecsr(const unsigned* __restrict__ bscat,
                                                 const int* __restrict__ bstart,
                                                 int* __restrict__ csr,
                                                 int* __restrict__ rowstart,
                                                 float* __restrict__ dis,
                                                 int N, int NB, int E){
  __shared__ int lcnt[BN];
  __shared__ int sc[BN];
  __shared__ int lcur[BN];
  __shared__ unsigned ebuf[EBUF];
  const int b = blockIdx.x;
  const int t = threadIdx.x;
  const int es = bstart[b], ee = bstart[b + 1];
  const int cnt = ee - es;

  if (t < BN) lcnt[t] = 0;
  __syncthreads();
  for (int i = t; i < cnt; i += 256){
    unsigned p = bscat[es + i];
    if (i < EBUF) ebuf[i] = p;
    atomicAdd(&lcnt[p >> 17], 1);
  }
  __syncthreads();
  if (t < BN) sc[t] = lcnt[t];
  __syncthreads();
  for (int off = 1; off < BN; off <<= 1){
    int v = (t < BN && t >= off) ? sc[t - off] : 0;
    __syncthreads();
    if (t < BN) sc[t] += v;
    __syncthreads();
  }
  if (t < BN){
    int excl = sc[t] - lcnt[t];
    lcur[t] = excl;
    int node = b * BN + t;
    if (node < N){
      rowstart[node] = es + excl;
      dis[node] = rsqrtf((float)(lcnt[t] + 1));
    }
  }
  if (b == NB - 1 && t == 0) rowstart[N] = E;
  __syncthreads();
  for (int i = t; i < cnt; i += 256){
    unsigned p = (i < EBUF) ? ebuf[i] : bscat[es + i];
    int pos = atomicAdd(&lcur[p >> 17], 1);
    csr[es + pos] = (int)((p & 0x1FFFFu) << 7);   // byte offset of hb row
  }
}

// ---- K6a: pre-swizzle W into B-fragment order, bf16 (once, 48 KB) ----
__global__ void k_wconv(const float* __restrict__ W, uint4* __restrict__ bpre){
  int j = blockIdx.x * blockDim.x + threadIdx.x;
  if (j >= 3072) return;
  int id = j & 1023, c = j >> 10;
  int cl = id & 63, s = (id >> 6) & 3, tl = id >> 8;
  int k = c * 128 + s * 32 + ((cl >> 4) << 3);
  int n = tl * 16 + (cl & 15);
  const float* wp = &W[(size_t)k * D_H + n];
  uint4 qv;
  qv.x = f2bf(wp[0])   | (f2bf(wp[64])  << 16);
  qv.y = f2bf(wp[128]) | (f2bf(wp[192]) << 16);
  qv.z = f2bf(wp[256]) | (f2bf(wp[320]) << 16);
  qv.w = f2bf(wp[384]) | (f2bf(wp[448]) << 16);
  bpre[j] = qv;
}

// ---- K6: LDS-free GEMM: hb = bf16( (x @ W_gcn) * dis[row] ) ----
__global__ __launch_bounds__(256) void k_gemm(const float* __restrict__ x,
                                              const uint4* __restrict__ bpre,
                                              const float* __restrict__ dis,
                                              unsigned short* __restrict__ hb, int N){
  const int t = threadIdx.x;
  const int w = t >> 6;
  const int l = t & 63;
  const int node0 = blockIdx.x * 64;
  const int row = node0 + w * 16 + (l & 15);
  const int rowc = row < N ? row : N - 1;
  const float* xr = x + (size_t)rowc * D_IN + ((l >> 4) << 3);

  f32x4 acc[4];
  #pragma unroll
  for (int nt = 0; nt < 4; nt++) acc[nt] = (f32x4){0.f, 0.f, 0.f, 0.f};

  #pragma unroll
  for (int c = 0; c < 3; c++){
    #pragma unroll
    for (int s = 0; s < 4; s++){
      const float* xp = xr + c * 128 + s * 32;
      float4 u0 = *(const float4*)xp;
      float4 u1 = *(const float4*)(xp + 4);
      uint4 pv;
      pv.x = f2bf(u0.x) | (f2bf(u0.y) << 16);
      pv.y = f2bf(u0.z) | (f2bf(u0.w) << 16);
      pv.z = f2bf(u1.x) | (f2bf(u1.y) << 16);
      pv.w = f2bf(u1.z) | (f2bf(u1.w) << 16);
      short8 a = *reinterpret_cast<short8*>(&pv);
      #pragma unroll
      for (int nt = 0; nt < 4; nt++){
        short8 b = *reinterpret_cast<const short8*>(&bpre[c * 1024 + (nt * 4 + s) * 64 + l]);
        acc[nt] = __builtin_amdgcn_mfma_f32_16x16x32_bf16(a, b, acc[nt], 0, 0, 0);
      }
    }
  }
  const int qd = l >> 4;
  const int col0 = l & 15;
  #pragma unroll
  for (int r = 0; r < 4; r++){
    int node = node0 + w * 16 + qd * 4 + r;
    if (node < N){
      float scale = dis[node];
      #pragma unroll
      for (int nt = 0; nt < 4; nt++)
        hb[(size_t)node * D_H + nt * 16 + col0] = (unsigned short)f2bf(acc[nt][r] * scale);
    }
  }
}

// ---- K7: fused quad-gather aggregation + relu + classifier + pooling ----
// wave per node. Lane covers 4 bf16 features (uint2 = 8 B); 16 lanes cover a
// 128 B row, so one load instruction gathers 4 edges (group g = lane>>4 picks
// edge e+g). Group merge via shfl_xor(16,32); per-node logit = relu(.)·wc
// reduced over 16 lanes; one atomicAdd into out[batch[i]].
__global__ __launch_bounds__(256) void k_agg(const unsigned short* __restrict__ hb,
                                             const int* __restrict__ csr,
                                             const int* __restrict__ rowstart,
                                             const float* __restrict__ dis,
                                             const float* __restrict__ bg,
                                             const int* __restrict__ batch,
                                             const float* __restrict__ wc,
                                             float* __restrict__ out, int N){
  int gid = blockIdx.x * 256 + (int)threadIdx.x;
  int i = __builtin_amdgcn_readfirstlane(gid >> 6);
  if (i >= N) return;
  const int l = threadIdx.x & 63;
  const int g = l >> 4;            // edge subgroup 0..3
  const int fo = (l & 15) << 3;    // byte offset of this lane's uint2 in a row
  const char* hbb = (const char*)hb;
  float a0 = 0.f, a1 = 0.f, a2 = 0.f, a3 = 0.f;

  // self-loop term hb[i] (= h[i]*dis[i]) — group 0 only
  {
    uint2 u = *(const uint2*)(hbb + ((size_t)(unsigned)i << 7) + fo);
    if (g == 0){
      a0 += __uint_as_float(u.x << 16);
      a1 += __uint_as_float(u.x & 0xffff0000u);
      a2 += __uint_as_float(u.y << 16);
      a3 += __uint_as_float(u.y & 0xffff0000u);
    }
  }
  const int rs = rowstart[i];
  const int re = rowstart[i + 1];
  int e = rs;
  for (; e + 16 <= re; e += 16){
    int b0 = csr[e + g];
    int b1 = csr[e + 4 + g];
    int b2 = csr[e + 8 + g];
    int b3 = csr[e + 12 + g];
    uint2 u0 = *(const uint2*)(hbb + (size_t)(unsigned)b0 + fo);
    uint2 u1 = *(const uint2*)(hbb + (size_t)(unsigned)b1 + fo);
    uint2 u2 = *(const uint2*)(hbb + (size_t)(unsigned)b2 + fo);
    uint2 u3 = *(const uint2*)(hbb + (size_t)(unsigned)b3 + fo);
    a0 += __uint_as_float(u0.x << 16);  a1 += __uint_as_float(u0.x & 0xffff0000u);
    a2 += __uint_as_float(u0.y << 16);  a3 += __uint_as_float(u0.y & 0xffff0000u);
    a0 += __uint_as_float(u1.x << 16);  a1 += __uint_as_float(u1.x & 0xffff0000u);
    a2 += __uint_as_float(u1.y << 16);  a3 += __uint_as_float(u1.y & 0xffff0000u);
    a0 += __uint_as_float(u2.x << 16);  a1 += __uint_as_float(u2.x & 0xffff0000u);
    a2 += __uint_as_float(u2.y << 16);  a3 += __uint_as_float(u2.y & 0xffff0000u);
    a0 += __uint_as_float(u3.x << 16);  a1 += __uint_as_float(u3.x & 0xffff0000u);
    a2 += __uint_as_float(u3.y << 16);  a3 += __uint_as_float(u3.y & 0xffff0000u);
  }
  for (; e < re; e += 4){
    int idx = e + g;
    bool val = idx < re;
    int b = csr[val ? idx : rs];
    uint2 u = *(const uint2*)(hbb + (size_t)(unsigned)b + fo);
    if (val){
      a0 += __uint_as_float(u.x << 16);
      a1 += __uint_as_float(u.x & 0xffff0000u);
      a2 += __uint_as_float(u.y << 16);
      a3 += __uint_as_float(u.y & 0xffff0000u);
    }
  }
  // merge the 4 edge-groups (feature layout identical across groups)
  a0 += __shfl_xor(a0, 16); a0 += __shfl_xor(a0, 32);
  a1 += __shfl_xor(a1, 16); a1 += __shfl_xor(a1, 32);
  a2 += __shfl_xor(a2, 16); a2 += __shfl_xor(a2, 32);
  a3 += __shfl_xor(a3, 16); a3 += __shfl_xor(a3, 32);

  if (g == 0){   // lanes 0..15 hold the full sums for features 4*(l&15)..+3
    float di = dis[i];
    int f0 = (l & 15) << 2;
    float4 bb = *(const float4*)(bg + f0);
    float4 ww = *(const float4*)(wc + f0);
    float v0 = a0 * di + bb.x; v0 = v0 > 0.f ? v0 : 0.f;
    float v1 = a1 * di + bb.y; v1 = v1 > 0.f ? v1 : 0.f;
    float v2 = a2 * di + bb.z; v2 = v2 > 0.f ? v2 : 0.f;
    float v3 = a3 * di + bb.w; v3 = v3 > 0.f ? v3 : 0.f;
    float s = v0 * ww.x + v1 * ww.y + v2 * ww.z + v3 * ww.w;
    s += __shfl_xor(s, 1);
    s += __shfl_xor(s, 2);
    s += __shfl_xor(s, 4);
    s += __shfl_xor(s, 8);
    if (l == 0) atomicAdd(&out[batch[i]], s);
  }
}

extern "C" void kernel_launch(void* const* d_in, const int* in_sizes, int n_in,
                              void* d_out, int out_size, void* d_ws, size_t ws_size,
                              hipStream_t stream){
  const float* x     = (const float*)d_in[0];
  const int*   ei    = (const int*)d_in[1];    // [2,E] flat: [0..E)=src, [E..2E)=dst
  const int*   batch = (const int*)d_in[2];
  const float* Wg    = (const float*)d_in[3];
  const float* bg    = (const float*)d_in[4];
  const float* wc    = (const float*)d_in[5];
  const float* bc    = (const float*)d_in[6];
  float* out = (float*)d_out;

  const int N = in_sizes[2];
  const int E = in_sizes[1] / 2;
  const int G = out_size;
  const int NB = (N + BN - 1) / BN;          // 782 for N=100000 (<=1024 assumed)
  const int chunk = (E + NBLK - 1) / NBLK;   // edges per sort chunk

  char* ws = (char*)d_ws;
  size_t off = 0;
  auto alloc = [&](size_t bytes) -> void* {
    void* p = ws + off;
    off += (bytes + 255) & ~(size_t)255;
    return p;
  };
  int*            hists    = (int*)           alloc((size_t)NBLK * NB * 4);
  int*            offs     = (int*)           alloc((size_t)NB * NBLK * 4);
  int*            bsum     = (int*)           alloc((size_t)NB * 4);
  int*            bstart   = (int*)           alloc((size_t)(NB + 1) * 4);
  unsigned*       bscat    = (unsigned*)      alloc((size_t)E * 4);
  int*            csr      = (int*)           alloc((size_t)E * 4);
  int*            rowstart = (int*)           alloc((size_t)(N + 1) * 4);
  float*          dis      = (float*)         alloc((size_t)N * 4);
  uint4*          bpre     = (uint4*)         alloc((size_t)3072 * 16);
  unsigned short* hb       = (unsigned short*)alloc((size_t)N * D_H * 2);

  k_oinit    <<<(G + 255) / 256, 256, 0, stream>>>(out, bc, G);
  k_wconv    <<<12, 256, 0, stream>>>(Wg, bpre);
  k_bcount2  <<<NBLK, 256, 0, stream>>>(ei, hists, E, NB, chunk);
  k_blkscan  <<<NB, NBLK, 0, stream>>>(hists, offs, bsum, NB);
  k_bscan    <<<1, 1024, 0, stream>>>(bsum, bstart, NB, E);
  k_bscatter2<<<NBLK, 256, 0, stream>>>(ei, bstart, offs, bscat, E, NB, chunk);
  k_nodecsr  <<<NB, 256, 0, stream>>>(bscat, bstart, csr, rowstart, dis, N, NB, E);
  k_gemm     <<<(N + 63) / 64, 256, 0, stream>>>(x, bpre, dis, hb, N);
  k_agg      <<<(N + 3) / 4, 256, 0, stream>>>(hb, csr, rowstart, dis, bg, batch, wc, out, N);
}